// Round 2
// baseline (488.818 us; speedup 1.0000x reference)
//
#include <hip/hip_runtime.h>
#include <hip/hip_bf16.h>

#define N_NODES 100000
#define N_EDGES 1600000
#define D 128

typedef float  floatx4 __attribute__((ext_vector_type(4)));
typedef __bf16 bf16x8  __attribute__((ext_vector_type(8)));

__device__ __forceinline__ unsigned rotl32(unsigned x, int d) {
    return (x << d) | (x >> (32 - d));
}

// JAX threefry2x32 with key (0, 42)  [key(42) -> (hi=0, lo=42)]
__device__ __forceinline__ void threefry_0_42(unsigned c0, unsigned c1,
                                              unsigned& o0, unsigned& o1) {
    const unsigned k0 = 0u, k1 = 42u;
    const unsigned k2 = 0x1BD11BDAu ^ k0 ^ k1;
    unsigned x0 = c0 + k0;
    unsigned x1 = c1 + k1;
#define TF_R4(r0, r1, r2, r3)                      \
    x0 += x1; x1 = rotl32(x1, r0); x1 ^= x0;       \
    x0 += x1; x1 = rotl32(x1, r1); x1 ^= x0;       \
    x0 += x1; x1 = rotl32(x1, r2); x1 ^= x0;       \
    x0 += x1; x1 = rotl32(x1, r3); x1 ^= x0;
    TF_R4(13, 15, 26, 6);  x0 += k1; x1 += k2 + 1u;
    TF_R4(17, 29, 16, 24); x0 += k2; x1 += k0 + 2u;
    TF_R4(13, 15, 26, 6);  x0 += k0; x1 += k1 + 3u;
    TF_R4(17, 29, 16, 24); x0 += k1; x1 += k2 + 4u;
    TF_R4(13, 15, 26, 6);  x0 += k2; x1 += k0 + 5u;
#undef TF_R4
    o0 = x0; o1 = x1;
}

// Partitionable threefry (modern JAX default): element i uses counter (0, i),
// bits = o0 ^ o1; keep iff uniform<0.5 <=> MSB(bits)==0.
__device__ __forceinline__ bool keep_elem(unsigned i) {
    unsigned o0, o1;
    threefry_0_42(0u, i, o0, o1);
    return (((o0 ^ o1) >> 31) == 0u);
}

__device__ __forceinline__ unsigned short f32_bf16(float f) {
    unsigned u = __float_as_uint(f);
    u += 0x7fffu + ((u >> 16) & 1u);   // RNE (inputs finite)
    return (unsigned short)(u >> 16);
}

// ---------------- Phase 1: fused dropout + GEMM (bf16 MFMA) ----------------
// Block g handles rows [g*32, g*32+32).
__global__ __launch_bounds__(256)
void k_gemm(const float* __restrict__ x, const float* __restrict__ W,
            unsigned short* __restrict__ hb) {
    __shared__ __align__(16) unsigned short Wt[128][136];  // Wt[n][k] = bf16(W[k][n])
    __shared__ __align__(16) unsigned short xs[32][136];

    const int t = threadIdx.x;
    const int g = blockIdx.x;

    // stage W transposed -> bf16
    for (int idx = t; idx < 128 * 128; idx += 256) {
        int k = idx >> 7, n = idx & 127;
        Wt[n][k] = f32_bf16(W[idx]);
    }

    // stage 32 x-rows with dropout applied (16 rows per half-tile)
    {
        int m  = t >> 4;            // 0..15
        int c0 = (t & 15) * 8;      // 0..120
        int r0 = g * 32 + m;
        const float* pa = x + r0 * D + c0;
        const float* pb = x + (r0 + 16) * D + c0;
        float va[8], vb[8];
        *(float4*)&va[0] = ((const float4*)pa)[0];
        *(float4*)&va[4] = ((const float4*)pa)[1];
        *(float4*)&vb[0] = ((const float4*)pb)[0];
        *(float4*)&vb[4] = ((const float4*)pb)[1];
        int ibase = r0 * D + c0;
#pragma unroll
        for (int j = 0; j < 8; ++j) {
            float fa = keep_elem((unsigned)(ibase + j))        ? 2.0f * va[j] : 0.0f;
            float fb = keep_elem((unsigned)(ibase + 2048 + j)) ? 2.0f * vb[j] : 0.0f;
            xs[m][c0 + j]      = f32_bf16(fa);
            xs[16 + m][c0 + j] = f32_bf16(fb);
        }
    }
    __syncthreads();

    // MFMA: 4 waves; wave -> (row half rt, 4 col-tiles)
    const int w  = t >> 6;
    const int l  = t & 63;
    const int rt = w >> 1;
    const int ctbase = (w & 1) * 4;
    const int mm = l & 15;              // A row / B col / D col
    const int q  = l >> 4;              // quad
    const int koff = q * 8;
    const unsigned short* xrow = &xs[rt * 16 + mm][0];
    const int growbase = g * 32 + rt * 16;

    for (int ci = 0; ci < 4; ++ci) {
        int ct = ctbase + ci;
        const unsigned short* wrow = &Wt[ct * 16 + mm][0];
        floatx4 acc = {0.f, 0.f, 0.f, 0.f};
#pragma unroll
        for (int kt = 0; kt < 4; ++kt) {
            bf16x8 a = *(const bf16x8*)(xrow + kt * 32 + koff);
            bf16x8 b = *(const bf16x8*)(wrow + kt * 32 + koff);
            acc = __builtin_amdgcn_mfma_f32_16x16x32_bf16(a, b, acc, 0, 0, 0);
        }
        int col = ct * 16 + mm;
#pragma unroll
        for (int reg = 0; reg < 4; ++reg) {
            int grow = growbase + q * 4 + reg;   // C/D: row = quad*4 + reg
            hb[grow * D + col] = f32_bf16(acc[reg]);
        }
    }
}

// ---------------- Phase 2: CSR build ----------------
__global__ __launch_bounds__(256)
void k_hist(const int* __restrict__ row, int* __restrict__ counts) {
    int e = blockIdx.x * 256 + threadIdx.x;
    if (e < N_EDGES) atomicAdd(&counts[row[e]], 1);
}

__global__ __launch_bounds__(256)
void k_scan1(const int* __restrict__ counts, int* __restrict__ offsets,
             int* __restrict__ blockSums, int n) {
    __shared__ int s[256];
    int t = threadIdx.x, gid = blockIdx.x * 256 + t;
    int v = (gid < n) ? counts[gid] : 0;
    s[t] = v;
    __syncthreads();
    for (int off = 1; off < 256; off <<= 1) {
        int add = (t >= off) ? s[t - off] : 0;
        __syncthreads();
        s[t] += add;
        __syncthreads();
    }
    if (gid < n) offsets[gid] = s[t] - v;          // exclusive within chunk
    if (t == 255) blockSums[blockIdx.x] = s[255];  // chunk total
}

__global__ __launch_bounds__(512)
void k_scan2(int* __restrict__ bs, int nb) {
    __shared__ int s[512];
    int t = threadIdx.x;
    int v = (t < nb) ? bs[t] : 0;
    s[t] = v;
    __syncthreads();
    for (int off = 1; off < 512; off <<= 1) {
        int add = (t >= off) ? s[t - off] : 0;
        __syncthreads();
        s[t] += add;
        __syncthreads();
    }
    if (t < nb) bs[t] = s[t] - v;                  // exclusive
}

__global__ __launch_bounds__(256)
void k_scan3(int* __restrict__ offsets, int* __restrict__ cursor,
             const int* __restrict__ blockSums, int n) {
    int gid = blockIdx.x * 256 + threadIdx.x;
    if (gid < n) {
        int o = offsets[gid] + blockSums[blockIdx.x];
        offsets[gid] = o;
        cursor[gid]  = o;
    }
}

__global__ __launch_bounds__(256)
void k_scatter(const int* __restrict__ row, const int* __restrict__ col,
               const float* __restrict__ val, int* __restrict__ cursor,
               int* __restrict__ csr_col, float* __restrict__ csr_val) {
    int e = blockIdx.x * 256 + threadIdx.x;
    if (e < N_EDGES) {
        int r = row[e];
        int pos = atomicAdd(&cursor[r], 1);
        csr_col[pos] = col[e];
        csr_val[pos] = val[e];
    }
}

// ---------------- Phase 3: gather SpMM + ReLU ----------------
__global__ __launch_bounds__(256)
void k_gather(const unsigned short* __restrict__ hb,
              const int* __restrict__ offsets, const int* __restrict__ counts,
              const int* __restrict__ csr_col, const float* __restrict__ csr_val,
              float* __restrict__ out) {
    int wid = blockIdx.x * 4 + (threadIdx.x >> 6);  // one wave per row
    int l   = threadIdx.x & 63;                     // lane -> cols 2l, 2l+1
    if (wid >= N_NODES) return;
    int start = offsets[wid];
    int end   = start + counts[wid];
    float a0 = 0.f, a1 = 0.f;
    for (int i = start; i < end; ++i) {
        int   c = csr_col[i];     // wave-uniform -> scalar load
        float v = csr_val[i];
        unsigned hv = *(const unsigned*)(hb + c * D + 2 * l);
        float h0 = __uint_as_float(hv << 16);
        float h1 = __uint_as_float(hv & 0xffff0000u);
        a0 = fmaf(v, h0, a0);
        a1 = fmaf(v, h1, a1);
    }
    float2 r;
    r.x = a0 > 0.f ? a0 : 0.f;
    r.y = a1 > 0.f ? a1 : 0.f;
    *(float2*)(out + wid * D + 2 * l) = r;
}

extern "C" void kernel_launch(void* const* d_in, const int* in_sizes, int n_in,
                              void* d_out, int out_size, void* d_ws, size_t ws_size,
                              hipStream_t stream) {
    const float* x    = (const float*)d_in[0];
    const float* W    = (const float*)d_in[1];
    const int*   arow = (const int*)d_in[2];
    const int*   acol = (const int*)d_in[3];
    const float* aval = (const float*)d_in[4];
    float* out = (float*)d_out;

    char* ws = (char*)d_ws;
    unsigned short* hb = (unsigned short*)ws;          // 25,600,000 B (h as bf16)
    size_t off = 25600000;
    int* counts    = (int*)(ws + off); off += 400000;
    int* offsets   = (int*)(ws + off); off += 400000;
    int* cursor    = (int*)(ws + off); off += 400000;
    int* blockSums = (int*)(ws + off); off += 2048;
    int*   csr_col = (int*)(ws + off); off += 6400000;
    float* csr_val = (float*)(ws + off); off += 6400000; // total ~39.6 MB

    hipMemsetAsync(counts, 0, 400000, stream);
    k_hist   <<<(N_EDGES + 255) / 256, 256, 0, stream>>>(arow, counts);
    k_scan1  <<<(N_NODES + 255) / 256, 256, 0, stream>>>(counts, offsets, blockSums, N_NODES);
    k_scan2  <<<1, 512, 0, stream>>>(blockSums, (N_NODES + 255) / 256);
    k_scan3  <<<(N_NODES + 255) / 256, 256, 0, stream>>>(offsets, cursor, blockSums, N_NODES);
    k_scatter<<<(N_EDGES + 255) / 256, 256, 0, stream>>>(arow, acol, aval, cursor, csr_col, csr_val);
    k_gemm   <<<3125, 256, 0, stream>>>(x, W, hb);
    k_gather <<<(N_NODES + 3) / 4, 256, 0, stream>>>(hb, offsets, counts, csr_col, csr_val, out);
}

// Round 3
// 400.807 us; speedup vs baseline: 1.2196x; 1.2196x over previous
//
#include <hip/hip_runtime.h>
#include <hip/hip_bf16.h>

#define N_NODES 100000
#define N_EDGES 1600000
#define D 128

typedef float  floatx4 __attribute__((ext_vector_type(4)));
typedef __bf16 bf16x8  __attribute__((ext_vector_type(8)));

__device__ __forceinline__ unsigned rotl32(unsigned x, int d) {
    return (x << d) | (x >> (32 - d));
}

// JAX threefry2x32 with key (0, 42)  [key(42) -> (hi=0, lo=42)]
__device__ __forceinline__ void threefry_0_42(unsigned c0, unsigned c1,
                                              unsigned& o0, unsigned& o1) {
    const unsigned k0 = 0u, k1 = 42u;
    const unsigned k2 = 0x1BD11BDAu ^ k0 ^ k1;
    unsigned x0 = c0 + k0;
    unsigned x1 = c1 + k1;
#define TF_R4(r0, r1, r2, r3)                      \
    x0 += x1; x1 = rotl32(x1, r0); x1 ^= x0;       \
    x0 += x1; x1 = rotl32(x1, r1); x1 ^= x0;       \
    x0 += x1; x1 = rotl32(x1, r2); x1 ^= x0;       \
    x0 += x1; x1 = rotl32(x1, r3); x1 ^= x0;
    TF_R4(13, 15, 26, 6);  x0 += k1; x1 += k2 + 1u;
    TF_R4(17, 29, 16, 24); x0 += k2; x1 += k0 + 2u;
    TF_R4(13, 15, 26, 6);  x0 += k0; x1 += k1 + 3u;
    TF_R4(17, 29, 16, 24); x0 += k1; x1 += k2 + 4u;
    TF_R4(13, 15, 26, 6);  x0 += k2; x1 += k0 + 5u;
#undef TF_R4
    o0 = x0; o1 = x1;
}

// Partitionable threefry (modern JAX default): element i uses counter (0, i),
// bits = o0 ^ o1; keep iff uniform<0.5 <=> MSB(bits)==0.
__device__ __forceinline__ bool keep_elem(unsigned i) {
    unsigned o0, o1;
    threefry_0_42(0u, i, o0, o1);
    return (((o0 ^ o1) >> 31) == 0u);
}

__device__ __forceinline__ unsigned short f32_bf16(float f) {
    unsigned u = __float_as_uint(f);
    u += 0x7fffu + ((u >> 16) & 1u);   // RNE (inputs finite)
    return (unsigned short)(u >> 16);
}

// ---------------- Phase 1: fused dropout + GEMM (bf16 MFMA) ----------------
__global__ __launch_bounds__(256)
void k_gemm(const float* __restrict__ x, const float* __restrict__ W,
            unsigned short* __restrict__ hb) {
    __shared__ __align__(16) unsigned short Wt[128][136];  // Wt[n][k] = bf16(W[k][n])
    __shared__ __align__(16) unsigned short xs[32][136];

    const int t = threadIdx.x;
    const int g = blockIdx.x;

    for (int idx = t; idx < 128 * 128; idx += 256) {
        int k = idx >> 7, n = idx & 127;
        Wt[n][k] = f32_bf16(W[idx]);
    }

    {
        int m  = t >> 4;            // 0..15
        int c0 = (t & 15) * 8;      // 0..120
        int r0 = g * 32 + m;
        const float* pa = x + r0 * D + c0;
        const float* pb = x + (r0 + 16) * D + c0;
        float va[8], vb[8];
        *(float4*)&va[0] = ((const float4*)pa)[0];
        *(float4*)&va[4] = ((const float4*)pa)[1];
        *(float4*)&vb[0] = ((const float4*)pb)[0];
        *(float4*)&vb[4] = ((const float4*)pb)[1];
        int ibase = r0 * D + c0;
#pragma unroll
        for (int j = 0; j < 8; ++j) {
            float fa = keep_elem((unsigned)(ibase + j))        ? 2.0f * va[j] : 0.0f;
            float fb = keep_elem((unsigned)(ibase + 2048 + j)) ? 2.0f * vb[j] : 0.0f;
            xs[m][c0 + j]      = f32_bf16(fa);
            xs[16 + m][c0 + j] = f32_bf16(fb);
        }
    }
    __syncthreads();

    const int w  = t >> 6;
    const int l  = t & 63;
    const int rt = w >> 1;
    const int ctbase = (w & 1) * 4;
    const int mm = l & 15;
    const int q  = l >> 4;
    const int koff = q * 8;
    const unsigned short* xrow = &xs[rt * 16 + mm][0];
    const int growbase = g * 32 + rt * 16;

    for (int ci = 0; ci < 4; ++ci) {
        int ct = ctbase + ci;
        const unsigned short* wrow = &Wt[ct * 16 + mm][0];
        floatx4 acc = {0.f, 0.f, 0.f, 0.f};
#pragma unroll
        for (int kt = 0; kt < 4; ++kt) {
            bf16x8 a = *(const bf16x8*)(xrow + kt * 32 + koff);
            bf16x8 b = *(const bf16x8*)(wrow + kt * 32 + koff);
            acc = __builtin_amdgcn_mfma_f32_16x16x32_bf16(a, b, acc, 0, 0, 0);
        }
        int col = ct * 16 + mm;
#pragma unroll
        for (int reg = 0; reg < 4; ++reg) {
            int grow = growbase + q * 4 + reg;
            hb[grow * D + col] = f32_bf16(acc[reg]);
        }
    }
}

// ---------------- Phase 2: CSR build ----------------
__global__ __launch_bounds__(256)
void k_hist(const int* __restrict__ row, int* __restrict__ counts) {
    int e4 = (blockIdx.x * 256 + threadIdx.x) * 4;
    if (e4 < N_EDGES) {                      // N_EDGES % 4 == 0
        int4 r = *(const int4*)(row + e4);
        atomicAdd(&counts[r.x], 1);
        atomicAdd(&counts[r.y], 1);
        atomicAdd(&counts[r.z], 1);
        atomicAdd(&counts[r.w], 1);
    }
}

__global__ __launch_bounds__(256)
void k_scan1(const int* __restrict__ counts, int* __restrict__ offsets,
             int* __restrict__ blockSums, int n) {
    __shared__ int s[256];
    int t = threadIdx.x, gid = blockIdx.x * 256 + t;
    int v = (gid < n) ? counts[gid] : 0;
    s[t] = v;
    __syncthreads();
    for (int off = 1; off < 256; off <<= 1) {
        int add = (t >= off) ? s[t - off] : 0;
        __syncthreads();
        s[t] += add;
        __syncthreads();
    }
    if (gid < n) offsets[gid] = s[t] - v;
    if (t == 255) blockSums[blockIdx.x] = s[255];
}

__global__ __launch_bounds__(512)
void k_scan2(int* __restrict__ bs, int nb) {
    __shared__ int s[512];
    int t = threadIdx.x;
    int v = (t < nb) ? bs[t] : 0;
    s[t] = v;
    __syncthreads();
    for (int off = 1; off < 512; off <<= 1) {
        int add = (t >= off) ? s[t - off] : 0;
        __syncthreads();
        s[t] += add;
        __syncthreads();
    }
    if (t < nb) bs[t] = s[t] - v;
}

__global__ __launch_bounds__(256)
void k_scan3(int* __restrict__ offsets, int* __restrict__ cursor,
             const int* __restrict__ blockSums, int n) {
    int gid = blockIdx.x * 256 + threadIdx.x;
    if (gid < n) {
        int o = offsets[gid] + blockSums[blockIdx.x];
        offsets[gid] = o;
        cursor[gid]  = o;
    }
}

// packed CSR entry: .x = col, .y = float bits of val
__global__ __launch_bounds__(256)
void k_scatter(const int* __restrict__ row, const int* __restrict__ col,
               const float* __restrict__ val, int* __restrict__ cursor,
               int2* __restrict__ csr) {
    int e = blockIdx.x * 256 + threadIdx.x;
    if (e < N_EDGES) {
        int r = row[e];
        int pos = atomicAdd(&cursor[r], 1);
        int2 ent;
        ent.x = col[e];
        ent.y = __float_as_int(val[e]);
        csr[pos] = ent;
    }
}

// ---------------- Phase 3: gather SpMM + ReLU (4x MLP unroll) ----------------
__device__ __forceinline__ void acc_edge(const unsigned short* __restrict__ hb,
                                         int2 e, int l2, float& a0, float& a1) {
    float v = __int_as_float(e.y);
    unsigned hv = *(const unsigned*)(hb + e.x * D + l2);
    float h0 = __uint_as_float(hv << 16);
    float h1 = __uint_as_float(hv & 0xffff0000u);
    a0 = fmaf(v, h0, a0);
    a1 = fmaf(v, h1, a1);
}

__global__ __launch_bounds__(256)
void k_gather(const unsigned short* __restrict__ hb,
              const int* __restrict__ offsets, const int* __restrict__ counts,
              const int2* __restrict__ csr, float* __restrict__ out) {
    int wid = blockIdx.x * 4 + (threadIdx.x >> 6);  // one wave per row
    int l2  = (threadIdx.x & 63) * 2;               // lane -> cols l2, l2+1
    if (wid >= N_NODES) return;
    int start = offsets[wid];
    int n     = counts[wid];
    float a0 = 0.f, a1 = 0.f;
    int i = 0;
    for (; i + 4 <= n; i += 4) {
        // 4 independent gathers in flight
        int2 e0 = csr[start + i];
        int2 e1 = csr[start + i + 1];
        int2 e2 = csr[start + i + 2];
        int2 e3 = csr[start + i + 3];
        unsigned hv0 = *(const unsigned*)(hb + e0.x * D + l2);
        unsigned hv1 = *(const unsigned*)(hb + e1.x * D + l2);
        unsigned hv2 = *(const unsigned*)(hb + e2.x * D + l2);
        unsigned hv3 = *(const unsigned*)(hb + e3.x * D + l2);
        float v0 = __int_as_float(e0.y), v1 = __int_as_float(e1.y);
        float v2 = __int_as_float(e2.y), v3 = __int_as_float(e3.y);
        a0 = fmaf(v0, __uint_as_float(hv0 << 16), a0);
        a1 = fmaf(v0, __uint_as_float(hv0 & 0xffff0000u), a1);
        a0 = fmaf(v1, __uint_as_float(hv1 << 16), a0);
        a1 = fmaf(v1, __uint_as_float(hv1 & 0xffff0000u), a1);
        a0 = fmaf(v2, __uint_as_float(hv2 << 16), a0);
        a1 = fmaf(v2, __uint_as_float(hv2 & 0xffff0000u), a1);
        a0 = fmaf(v3, __uint_as_float(hv3 << 16), a0);
        a1 = fmaf(v3, __uint_as_float(hv3 & 0xffff0000u), a1);
    }
    for (; i < n; ++i) {
        int2 e = csr[start + i];
        acc_edge(hb, e, l2, a0, a1);
    }
    float2 r;
    r.x = a0 > 0.f ? a0 : 0.f;
    r.y = a1 > 0.f ? a1 : 0.f;
    *(float2*)(out + wid * D + l2) = r;
}

extern "C" void kernel_launch(void* const* d_in, const int* in_sizes, int n_in,
                              void* d_out, int out_size, void* d_ws, size_t ws_size,
                              hipStream_t stream) {
    const float* x    = (const float*)d_in[0];
    const float* W    = (const float*)d_in[1];
    const int*   arow = (const int*)d_in[2];
    const int*   acol = (const int*)d_in[3];
    const float* aval = (const float*)d_in[4];
    float* out = (float*)d_out;

    char* ws = (char*)d_ws;
    unsigned short* hb = (unsigned short*)ws;          // 25,600,000 B (h as bf16)
    size_t off = 25600000;
    int* counts    = (int*)(ws + off); off += 400000;
    int* offsets   = (int*)(ws + off); off += 400000;
    int* cursor    = (int*)(ws + off); off += 400000;
    int* blockSums = (int*)(ws + off); off += 2048;
    int2* csr      = (int2*)(ws + off); off += 12800000; // packed (col, val)

    hipMemsetAsync(counts, 0, 400000, stream);
    k_hist   <<<(N_EDGES / 4 + 255) / 256, 256, 0, stream>>>(arow, counts);
    k_scan1  <<<(N_NODES + 255) / 256, 256, 0, stream>>>(counts, offsets, blockSums, N_NODES);
    k_scan2  <<<1, 512, 0, stream>>>(blockSums, (N_NODES + 255) / 256);
    k_scan3  <<<(N_NODES + 255) / 256, 256, 0, stream>>>(offsets, cursor, blockSums, N_NODES);
    k_scatter<<<(N_EDGES + 255) / 256, 256, 0, stream>>>(arow, acol, aval, cursor, csr);
    k_gemm   <<<3125, 256, 0, stream>>>(x, W, hb);
    k_gather <<<(N_NODES + 3) / 4, 256, 0, stream>>>(hb, offsets, counts, csr, out);
}

// Round 4
// 267.447 us; speedup vs baseline: 1.8277x; 1.4986x over previous
//
#include <hip/hip_runtime.h>
#include <hip/hip_bf16.h>

#define N_NODES 100000
#define N_EDGES 1600000
#define D 128
#define NBUCKETS 391          // ceil(N_NODES/256), bucket = 256 rows
#define BUCKET_EDGES 4096     // edges per k_bhist/k_bucket block
#define NBLK1 391             // ceil(N_EDGES/BUCKET_EDGES)
#define SORT_CAP 5120         // max entries/bucket staged in LDS (mean 4096, sigma 64)

typedef float  floatx4 __attribute__((ext_vector_type(4)));
typedef __bf16 bf16x8  __attribute__((ext_vector_type(8)));

__device__ __forceinline__ unsigned rotl32(unsigned x, int d) {
    return (x << d) | (x >> (32 - d));
}

// JAX threefry2x32 with key (0, 42)
__device__ __forceinline__ void threefry_0_42(unsigned c0, unsigned c1,
                                              unsigned& o0, unsigned& o1) {
    const unsigned k0 = 0u, k1 = 42u;
    const unsigned k2 = 0x1BD11BDAu ^ k0 ^ k1;
    unsigned x0 = c0 + k0;
    unsigned x1 = c1 + k1;
#define TF_R4(r0, r1, r2, r3)                      \
    x0 += x1; x1 = rotl32(x1, r0); x1 ^= x0;       \
    x0 += x1; x1 = rotl32(x1, r1); x1 ^= x0;       \
    x0 += x1; x1 = rotl32(x1, r2); x1 ^= x0;       \
    x0 += x1; x1 = rotl32(x1, r3); x1 ^= x0;
    TF_R4(13, 15, 26, 6);  x0 += k1; x1 += k2 + 1u;
    TF_R4(17, 29, 16, 24); x0 += k2; x1 += k0 + 2u;
    TF_R4(13, 15, 26, 6);  x0 += k0; x1 += k1 + 3u;
    TF_R4(17, 29, 16, 24); x0 += k1; x1 += k2 + 4u;
    TF_R4(13, 15, 26, 6);  x0 += k2; x1 += k0 + 5u;
#undef TF_R4
    o0 = x0; o1 = x1;
}

// Partitionable threefry (modern JAX default): element i -> counter (0, i),
// bits = o0 ^ o1; keep iff MSB(bits)==0.
__device__ __forceinline__ bool keep_elem(unsigned i) {
    unsigned o0, o1;
    threefry_0_42(0u, i, o0, o1);
    return (((o0 ^ o1) >> 31) == 0u);
}

__device__ __forceinline__ unsigned short f32_bf16(float f) {
    unsigned u = __float_as_uint(f);
    u += 0x7fffu + ((u >> 16) & 1u);   // RNE
    return (unsigned short)(u >> 16);
}

// ---------------- Phase 1: fused dropout + GEMM (bf16 MFMA) ----------------
__global__ __launch_bounds__(256)
void k_gemm(const float* __restrict__ x, const float* __restrict__ W,
            unsigned short* __restrict__ hb) {
    __shared__ __align__(16) unsigned short Wt[128][136];  // Wt[n][k] = bf16(W[k][n])
    __shared__ __align__(16) unsigned short xs[32][136];

    const int t = threadIdx.x;
    const int g = blockIdx.x;

    for (int idx = t; idx < 128 * 128; idx += 256) {
        int k = idx >> 7, n = idx & 127;
        Wt[n][k] = f32_bf16(W[idx]);
    }

    {
        int m  = t >> 4;
        int c0 = (t & 15) * 8;
        int r0 = g * 32 + m;
        const float* pa = x + r0 * D + c0;
        const float* pb = x + (r0 + 16) * D + c0;
        float va[8], vb[8];
        *(float4*)&va[0] = ((const float4*)pa)[0];
        *(float4*)&va[4] = ((const float4*)pa)[1];
        *(float4*)&vb[0] = ((const float4*)pb)[0];
        *(float4*)&vb[4] = ((const float4*)pb)[1];
        int ibase = r0 * D + c0;
#pragma unroll
        for (int j = 0; j < 8; ++j) {
            float fa = keep_elem((unsigned)(ibase + j))        ? 2.0f * va[j] : 0.0f;
            float fb = keep_elem((unsigned)(ibase + 2048 + j)) ? 2.0f * vb[j] : 0.0f;
            xs[m][c0 + j]      = f32_bf16(fa);
            xs[16 + m][c0 + j] = f32_bf16(fb);
        }
    }
    __syncthreads();

    const int w  = t >> 6;
    const int l  = t & 63;
    const int rt = w >> 1;
    const int ctbase = (w & 1) * 4;
    const int mm = l & 15;
    const int q  = l >> 4;
    const int koff = q * 8;
    const unsigned short* xrow = &xs[rt * 16 + mm][0];
    const int growbase = g * 32 + rt * 16;

    for (int ci = 0; ci < 4; ++ci) {
        int ct = ctbase + ci;
        const unsigned short* wrow = &Wt[ct * 16 + mm][0];
        floatx4 acc = {0.f, 0.f, 0.f, 0.f};
#pragma unroll
        for (int kt = 0; kt < 4; ++kt) {
            bf16x8 a = *(const bf16x8*)(xrow + kt * 32 + koff);
            bf16x8 b = *(const bf16x8*)(wrow + kt * 32 + koff);
            acc = __builtin_amdgcn_mfma_f32_16x16x32_bf16(a, b, acc, 0, 0, 0);
        }
        int col = ct * 16 + mm;
#pragma unroll
        for (int reg = 0; reg < 4; ++reg) {
            int grow = growbase + q * 4 + reg;
            hb[grow * D + col] = f32_bf16(acc[reg]);
        }
    }
}

// ---------------- Phase 2: bucketed CSR build ----------------
// 2a: per-block LDS histogram over 391 buckets, one global atomic per (block,bucket)
__global__ __launch_bounds__(256)
void k_bhist(const int* __restrict__ row, int* __restrict__ bcnt) {
    __shared__ int h[NBUCKETS];
    const int t = threadIdx.x;
    for (int i = t; i < NBUCKETS; i += 256) h[i] = 0;
    __syncthreads();
    int base = blockIdx.x * BUCKET_EDGES;
#pragma unroll
    for (int k = 0; k < 4; ++k) {
        int e4 = base + (k * 256 + t) * 4;
        if (e4 < N_EDGES) {
            int4 r = *(const int4*)(row + e4);
            atomicAdd(&h[r.x >> 8], 1);
            atomicAdd(&h[r.y >> 8], 1);
            atomicAdd(&h[r.z >> 8], 1);
            atomicAdd(&h[r.w >> 8], 1);
        }
    }
    __syncthreads();
    for (int i = t; i < NBUCKETS; i += 256)
        if (h[i]) atomicAdd(&bcnt[i], h[i]);
}

// 2b: scan bucket counts -> bucket starts + cursors; write sentinels
__global__ __launch_bounds__(512)
void k_bscan(const int* __restrict__ bcnt, int* __restrict__ bstart,
             int* __restrict__ bcur, int* __restrict__ offsets) {
    __shared__ int s[512];
    int t = threadIdx.x;
    int v = (t < NBUCKETS) ? bcnt[t] : 0;
    s[t] = v;
    __syncthreads();
    for (int off = 1; off < 512; off <<= 1) {
        int a = (t >= off) ? s[t - off] : 0;
        __syncthreads();
        s[t] += a;
        __syncthreads();
    }
    if (t < NBUCKETS) {
        int st = s[t] - v;
        bstart[t] = st;
        bcur[t]   = st;
    }
    if (t == 0) {
        bstart[NBUCKETS]  = N_EDGES;
        offsets[N_NODES]  = N_EDGES;
    }
}

// 2c: bucket scatter — per-block chunk reservation, packed entries
// entry.x = col | (rowlow << 17), entry.y = float bits of val
__global__ __launch_bounds__(256)
void k_bucket(const int* __restrict__ row, const int* __restrict__ col,
              const float* __restrict__ val, int* __restrict__ bcur,
              int2* __restrict__ buf) {
    __shared__ int h[NBUCKETS];
    __shared__ int lbase[NBUCKETS];
    const int t = threadIdx.x;
    for (int i = t; i < NBUCKETS; i += 256) h[i] = 0;
    __syncthreads();

    int rows[16], cols[16];
    float vals[16];
    int base = blockIdx.x * BUCKET_EDGES;
#pragma unroll
    for (int k = 0; k < 4; ++k) {
        int e4 = base + (k * 256 + t) * 4;
        if (e4 < N_EDGES) {
            *(int4*)&rows[k * 4]   = *(const int4*)(row + e4);
            *(int4*)&cols[k * 4]   = *(const int4*)(col + e4);
            *(float4*)&vals[k * 4] = *(const float4*)(val + e4);
        } else {
            rows[k * 4] = rows[k * 4 + 1] = rows[k * 4 + 2] = rows[k * 4 + 3] = -1;
        }
    }
#pragma unroll
    for (int j = 0; j < 16; ++j)
        if (rows[j] >= 0) atomicAdd(&h[rows[j] >> 8], 1);
    __syncthreads();

    for (int i = t; i < NBUCKETS; i += 256) {
        int c = h[i];
        lbase[i] = c ? atomicAdd(&bcur[i], c) : 0;
    }
    __syncthreads();
    for (int i = t; i < NBUCKETS; i += 256) h[i] = 0;
    __syncthreads();

#pragma unroll
    for (int j = 0; j < 16; ++j) {
        if (rows[j] >= 0) {
            int b = rows[j] >> 8;
            int pos = lbase[b] + atomicAdd(&h[b], 1);
            int2 ent;
            ent.x = cols[j] | ((rows[j] & 255) << 17);
            ent.y = __float_as_int(vals[j]);
            buf[pos] = ent;
        }
    }
}

// 2d: per-bucket counting sort (in LDS), in-place back to buf; writes row offsets
__global__ __launch_bounds__(256)
void k_sort(const int* __restrict__ bstart, int2* __restrict__ buf,
            int* __restrict__ offsets) {
    __shared__ int2 ents[SORT_CAP];
    __shared__ int s[256];
    __shared__ int cur[256];
    const int b = blockIdx.x, t = threadIdx.x;
    const int s0 = bstart[b];
    const int n  = bstart[b + 1] - s0;

    for (int i = t; i < n; i += 256) ents[i] = buf[s0 + i];
    s[t] = 0;
    __syncthreads();
    for (int i = t; i < n; i += 256) atomicAdd(&s[ents[i].x >> 17], 1);
    __syncthreads();
    int v = s[t];
    for (int off = 1; off < 256; off <<= 1) {
        int a = (t >= off) ? s[t - off] : 0;
        __syncthreads();
        s[t] += a;
        __syncthreads();
    }
    int excl = s[t] - v;
    int grow = (b << 8) + t;
    if (grow < N_NODES) offsets[grow] = s0 + excl;
    cur[t] = excl;
    __syncthreads();
    for (int i = t; i < n; i += 256) {
        int2 e = ents[i];
        int rl = e.x >> 17;
        int p  = s0 + atomicAdd(&cur[rl], 1);
        int2 outent;
        outent.x = e.x & 0x1FFFF;
        outent.y = e.y;
        buf[p] = outent;       // safe: source fully staged in LDS
    }
}

// ---------------- Phase 3: gather SpMM + ReLU (8x MLP) ----------------
__global__ __launch_bounds__(256)
void k_gather(const unsigned short* __restrict__ hb,
              const int* __restrict__ offsets,
              const int2* __restrict__ csr, float* __restrict__ out) {
    int wid = blockIdx.x * 4 + (threadIdx.x >> 6);  // one wave per row
    int l2  = (threadIdx.x & 63) * 2;
    if (wid >= N_NODES) return;
    int start = offsets[wid];
    int n     = offsets[wid + 1] - start;
    float a0 = 0.f, a1 = 0.f;
    int i = 0;
    for (; i + 8 <= n; i += 8) {
        int2 e[8];
        unsigned hv[8];
#pragma unroll
        for (int j = 0; j < 8; ++j) e[j] = csr[start + i + j];
#pragma unroll
        for (int j = 0; j < 8; ++j) hv[j] = *(const unsigned*)(hb + e[j].x * D + l2);
#pragma unroll
        for (int j = 0; j < 8; ++j) {
            float v = __int_as_float(e[j].y);
            a0 = fmaf(v, __uint_as_float(hv[j] << 16), a0);
            a1 = fmaf(v, __uint_as_float(hv[j] & 0xffff0000u), a1);
        }
    }
    for (; i + 4 <= n; i += 4) {
        int2 e[4];
        unsigned hv[4];
#pragma unroll
        for (int j = 0; j < 4; ++j) e[j] = csr[start + i + j];
#pragma unroll
        for (int j = 0; j < 4; ++j) hv[j] = *(const unsigned*)(hb + e[j].x * D + l2);
#pragma unroll
        for (int j = 0; j < 4; ++j) {
            float v = __int_as_float(e[j].y);
            a0 = fmaf(v, __uint_as_float(hv[j] << 16), a0);
            a1 = fmaf(v, __uint_as_float(hv[j] & 0xffff0000u), a1);
        }
    }
    for (; i < n; ++i) {
        int2 e = csr[start + i];
        float v = __int_as_float(e.y);
        unsigned hv = *(const unsigned*)(hb + e.x * D + l2);
        a0 = fmaf(v, __uint_as_float(hv << 16), a0);
        a1 = fmaf(v, __uint_as_float(hv & 0xffff0000u), a1);
    }
    float2 r;
    r.x = a0 > 0.f ? a0 : 0.f;
    r.y = a1 > 0.f ? a1 : 0.f;
    *(float2*)(out + wid * D + l2) = r;
}

extern "C" void kernel_launch(void* const* d_in, const int* in_sizes, int n_in,
                              void* d_out, int out_size, void* d_ws, size_t ws_size,
                              hipStream_t stream) {
    const float* x    = (const float*)d_in[0];
    const float* W    = (const float*)d_in[1];
    const int*   arow = (const int*)d_in[2];
    const int*   acol = (const int*)d_in[3];
    const float* aval = (const float*)d_in[4];
    float* out = (float*)d_out;

    char* ws = (char*)d_ws;
    unsigned short* hb = (unsigned short*)ws;            // 25,600,000 B
    size_t off = 25600000;
    int* offsets = (int*)(ws + off); off += 400016;      // N_NODES+1 ints
    int* bcnt    = (int*)(ws + off); off += 1568;        // NBUCKETS+1
    int* bstart  = (int*)(ws + off); off += 1568;
    int* bcur    = (int*)(ws + off); off += 1568;
    int2* buf    = (int2*)(ws + off); off += 12800000;   // packed edges -> final CSR
    // total ~38.8 MB

    hipMemsetAsync(bcnt, 0, 1568, stream);
    k_bhist <<<NBLK1, 256, 0, stream>>>(arow, bcnt);
    k_bscan <<<1, 512, 0, stream>>>(bcnt, bstart, bcur, offsets);
    k_bucket<<<NBLK1, 256, 0, stream>>>(arow, acol, aval, bcur, buf);
    k_sort  <<<NBUCKETS, 256, 0, stream>>>(bstart, buf, offsets);
    k_gemm  <<<3125, 256, 0, stream>>>(x, W, hb);
    k_gather<<<(N_NODES + 3) / 4, 256, 0, stream>>>(hb, offsets, buf, out);
}